// Round 12
// baseline (175.716 us; speedup 1.0000x reference)
//
#include <hip/hip_runtime.h>
#include <hip/hip_fp16.h>

#define NN 8192
#define INF 256
#define OUTF 128
#define LOG2E 1.44269504088896340736f

typedef float f32x4 __attribute__((ext_vector_type(4)));
typedef float f32x16 __attribute__((ext_vector_type(16)));
typedef __fp16 h16x8 __attribute__((ext_vector_type(8)));
typedef __fp16 h16x4 __attribute__((ext_vector_type(4)));
typedef __fp16 h16x2 __attribute__((ext_vector_type(2)));
typedef int i32x4 __attribute__((ext_vector_type(4)));

__device__ __forceinline__ void gload_lds16(const void* g, void* l) {
  __builtin_amdgcn_global_load_lds(
      (const __attribute__((address_space(1))) unsigned int*)g,
      (__attribute__((address_space(3))) unsigned int*)l, 16, 0, 0);
}

// order-preserving float->uint encoding (for atomicMax-based global max)
__device__ __forceinline__ unsigned encf(float f) {
  int b = __float_as_int(f);
  return b >= 0 ? ((unsigned)b | 0x80000000u) : ~(unsigned)b;
}
__device__ __forceinline__ float decf(unsigned u) {
  int b = (u & 0x80000000u) ? (int)(u & 0x7FFFFFFFu) : ~(int)u;
  return __int_as_float(b);
}

// ---------------- K0: W -> WT_perm f16; also zeroes GMu (runs before kf)
__global__ __launch_bounds__(256) void k0_wt(const float* __restrict__ W1,
                                             const float* __restrict__ W2,
                                             __fp16* __restrict__ WT,
                                             unsigned* __restrict__ GMu) {
  if (blockIdx.x == 0 && threadIdx.x < 2) GMu[threadIdx.x] = 0u;
  int m = blockIdx.x * 256 + threadIdx.x;  // 8192 chunks of 16B
  int h = m >> 12;
  int r = m & 4095;
  int c = r >> 5;
  int kb = (r >> 1) & 15;
  int hh = r & 1;
  const float* W = h ? W2 : W1;
  float v[8];
#pragma unroll
  for (int s = 0; s < 8; ++s) {
    int koff = 4 * hh + (s & 3) + 8 * (s >> 2);
    v[s] = W[(kb * 16 + koff) * OUTF + c];
  }
  union { h16x2 h2[4]; i32x4 q; } u;
  u.h2[0] = __builtin_amdgcn_cvt_pkrtz(v[0], v[1]);
  u.h2[1] = __builtin_amdgcn_cvt_pkrtz(v[2], v[3]);
  u.h2[2] = __builtin_amdgcn_cvt_pkrtz(v[4], v[5]);
  u.h2[3] = __builtin_amdgcn_cvt_pkrtz(v[6], v[7]);
  *(i32x4*)(WT + (size_t)h * 32768 + c * 256 + kb * 16 + hh * 8) = u.q;
}

// ---------------- KF: fused kb_pack (blocks 256..2303) + k1_h (blocks 0..255).
// k1 blocks dispatch FIRST so the h-projection runs under the adj HBM stream.
__global__ __launch_bounds__(256) void kf(
    const int* __restrict__ adj, unsigned short* __restrict__ adjb,
    const float* __restrict__ inp, const __fp16* __restrict__ WT,
    const float* __restrict__ a1, const float* __restrict__ a2,
    __fp16* __restrict__ hT2, float* __restrict__ S, float* __restrict__ D,
    unsigned* __restrict__ GMu) {
  __shared__ __align__(16) float hl[2][32][136];
  if (blockIdx.x >= 256) {
    // ---- kb_pack: adj -> u16 bitmask row-major [row][j16]
    int gid = (blockIdx.x - 256) * 256 + threadIdx.x;
#pragma unroll
    for (int it = 0; it < 8; ++it) {
      size_t c = (size_t)it * 524288 + gid;     // u16-chunk index, 4M total
      const int* p = adj + c * 16;
      i32x4 v0 = *(const i32x4*)(p);
      i32x4 v1 = *(const i32x4*)(p + 4);
      i32x4 v2 = *(const i32x4*)(p + 8);
      i32x4 v3 = *(const i32x4*)(p + 12);
      unsigned int b = 0;
#pragma unroll
      for (int k = 0; k < 4; ++k) {
        b |= (v0[k] != 0 ? 1u : 0u) << k;
        b |= (v1[k] != 0 ? 1u : 0u) << (4 + k);
        b |= (v2[k] != 0 ? 1u : 0u) << (8 + k);
        b |= (v3[k] != 0 ? 1u : 0u) << (12 + k);
      }
      adjb[c] = (unsigned short)b;
    }
    return;
  }
  // ---- k1: h = inp@W via MFMA; 4 waves = 2 heads x 2 nf-halves, 32 rows/block
  int tid = threadIdx.x;
  int w = tid >> 6;
  int head = w >> 1, half = w & 1;
  int l = tid & 63;
  int lr = l & 31, g = l >> 5;
  int i0 = blockIdx.x * 32;
  const __fp16* WTh = WT + (size_t)head * 32768;
  f32x16 acc[2];
#pragma unroll
  for (int nf2 = 0; nf2 < 2; ++nf2)
#pragma unroll
    for (int e = 0; e < 16; ++e) acc[nf2][e] = 0.0f;
  const float* ip = inp + (size_t)(i0 + lr) * INF;
#pragma unroll
  for (int kb = 0; kb < 16; ++kb) {
    f32x4 q0 = *(const f32x4*)(ip + kb * 16 + 4 * g);
    f32x4 q1 = *(const f32x4*)(ip + kb * 16 + 8 + 4 * g);
    union { h16x2 h2[4]; h16x8 h8; } ua;
    ua.h2[0] = __builtin_amdgcn_cvt_pkrtz(q0[0], q0[1]);
    ua.h2[1] = __builtin_amdgcn_cvt_pkrtz(q0[2], q0[3]);
    ua.h2[2] = __builtin_amdgcn_cvt_pkrtz(q1[0], q1[1]);
    ua.h2[3] = __builtin_amdgcn_cvt_pkrtz(q1[2], q1[3]);
#pragma unroll
    for (int nf2 = 0; nf2 < 2; ++nf2) {
      int nf = half * 2 + nf2;
      h16x8 b = *(const h16x8*)(WTh + (nf * 32 + lr) * 256 + kb * 16 + g * 8);
      acc[nf2] = __builtin_amdgcn_mfma_f32_32x32x16_f16(ua.h8, b, acc[nf2], 0, 0, 0);
    }
  }
#pragma unroll
  for (int nf2 = 0; nf2 < 2; ++nf2) {
    int nf = half * 2 + nf2;
#pragma unroll
    for (int r = 0; r < 16; ++r) {
      int row = (r & 3) + 8 * (r >> 2) + 4 * g;
      hl[head][row][nf * 32 + lr] = acc[nf2][r];
    }
  }
  __syncthreads();
  if (half == 0) {
    const float* av = head ? a2 : a1;
    float s = 0.f, d = 0.f;
#pragma unroll
    for (int cc = 0; cc < 64; cc += 4) {
      int c = g * 64 + cc;
      f32x4 hv = *(const f32x4*)&hl[head][lr][c];
      f32x4 as = *(const f32x4*)(av + c);
      f32x4 ad = *(const f32x4*)(av + 128 + c);
      s += hv[0] * as[0] + hv[1] * as[1] + hv[2] * as[2] + hv[3] * as[3];
      d += hv[0] * ad[0] + hv[1] * ad[1] + hv[2] * ad[2] + hv[3] * ad[3];
    }
    s += __shfl_xor(s, 32);
    d += __shfl_xor(d, 32);
    float dl = d * LOG2E;
    if (g == 0) {
      S[(size_t)head * NN + i0 + lr] = s * LOG2E;
      D[(size_t)head * NN + i0 + lr] = dl;
    }
    float dmax = dl;
#pragma unroll
    for (int off = 1; off < 32; off <<= 1) dmax = fmaxf(dmax, __shfl_xor(dmax, off));
    if (l == 0) atomicMax(GMu + head, encf(dmax));
  }
  // hT2 emission: per head 512 chunks(16B); each wave emits 4x64
  __fp16* hTh = hT2 + (size_t)head * (NN * OUTF);
#pragma unroll
  for (int it2 = 0; it2 < 4; ++it2) {
    int id = (half * 4 + it2) * 64 + l;   // [0,512)
    int jb = id >> 8;
    int sub = id & 255;
    int nf = sub >> 6, lq = sub & 63;
    int lqr = lq & 31, lqg = lq >> 5;
    float v[8];
#pragma unroll
    for (int s2 = 0; s2 < 8; ++s2) {
      int kloc = 4 * lqg + (s2 & 3) + 8 * (s2 >> 2);   // MFMA k-map (A/B identical)
      v[s2] = hl[head][jb * 16 + kloc][nf * 32 + lqr];
    }
    union { h16x2 h2[4]; i32x4 q; } u2;
    u2.h2[0] = __builtin_amdgcn_cvt_pkrtz(v[0], v[1]);
    u2.h2[1] = __builtin_amdgcn_cvt_pkrtz(v[2], v[3]);
    u2.h2[2] = __builtin_amdgcn_cvt_pkrtz(v[4], v[5]);
    u2.h2[3] = __builtin_amdgcn_cvt_pkrtz(v[6], v[7]);
    *(i32x4*)(hTh + (size_t)((i0 >> 4) + jb) * 2048 + sub * 8) = u2.q;
  }
}

// ---------------- K2: bitmask softmax + PV, 32x32x16 MFMA, 64 rows/wave.
// ZERO-STAGING: B-frags read directly from L2-resident hT2 into registers,
// double-buffered one jstep ahead (BA/BB, static indexing). D window (8KB)
// parked in otherwise-idle LDS (broadcast ds_read, no L1 thrash). One barrier
// total (prologue). Masks prefetched in registers.
__global__ __launch_bounds__(256, 2) void k2_attn(
    const unsigned short* __restrict__ adjb, const __fp16* __restrict__ hT2,
    const float* __restrict__ S, const float* __restrict__ D,
    const unsigned* __restrict__ GMu, __fp16* __restrict__ NUM,
    float* __restrict__ DEN) {
  __shared__ __align__(16) float Dw[2][1024];  // 8 KB
  int tid = threadIdx.x;
  int w = tid >> 6;
  int l = tid & 63;
  int lr = l & 31, g2 = l >> 5;
  int h = w >> 1, rq = w & 1;
  int rb = blockIdx.x >> 3, js = blockIdx.x & 7;
  int i0 = rb * 128;
  int jwin = js * 1024, jw16 = js * 64;
  int base = i0 + rq * 64;
  int row0 = base + lr, row1 = base + 32 + lr;
  float gm = decf(GMu[h]);
  float sf0 = S[(size_t)h * NN + row0];
  float sf1 = S[(size_t)h * NN + row1];
  float t0 = sf0 + gm, t1 = sf1 + gm;
  float cn0 = -fmaxf(t0, 0.2f * t0) - 1000.0f;
  float cn1 = -fmaxf(t1, 0.2f * t1) - 1000.0f;
  float Ac0 = sf0 + cn0, Bc0 = 0.2f * sf0 + cn0;
  float Ac1 = sf1 + cn1, Bc1 = 0.2f * sf1 + cn1;

  // D window -> LDS (linear dest; wave-uniform base + lane*16)
#pragma unroll
  for (int q = 0; q < 2; ++q) {
    int idx = q * 256 + tid;
    int hh = idx >> 8, jj = idx & 255;
    gload_lds16(D + (size_t)hh * NN + jwin + jj * 4, (char*)&Dw[0][0] + idx * 16);
  }

  f32x16 acc[2][4];
#pragma unroll
  for (int f = 0; f < 2; ++f)
#pragma unroll
    for (int nf = 0; nf < 4; ++nf)
#pragma unroll
      for (int e = 0; e < 16; ++e) acc[f][nf][e] = 0.0f;
  float dsum0 = 0.f, dsum1 = 0.f;

  const __fp16* Bbase = hT2 + (size_t)h * (NN * OUTF) + (size_t)jw16 * 2048 + l * 8;
  h16x8 BA[8], BB[8];
  auto LOADB = [&](int jstep, h16x8* Bn) {
#pragma unroll
    for (int q = 0; q < 8; ++q) {     // q = kk*4 + nf
      int kk = q >> 2, nf = q & 3;
      Bn[q] = *(const h16x8*)(Bbase + (size_t)(jstep * 2 + kk) * 2048 + nf * 512);
    }
  };

  const unsigned short* mrow0 = adjb + (size_t)row0 * 512 + jw16;
  const unsigned short* mrow1 = adjb + (size_t)row1 * 512 + jw16;
  i32x4 mreg0 = *(const i32x4*)(mrow0), mnext0 = *(const i32x4*)(mrow0 + 8);
  i32x4 mreg1 = *(const i32x4*)(mrow1), mnext1 = *(const i32x4*)(mrow1 + 8);

  const h16x2 ones = {(__fp16)1.0f, (__fp16)1.0f};
  h16x8 P[2][2];   // [f][kk], compile-time indexed only
  const float* DwH = &Dw[h][0] + 4 * g2;

  auto SOFTMAX = [&](int jn, unsigned dwm0, unsigned dwm1) {
#pragma unroll
    for (int kk = 0; kk < 2; ++kk) {
      int kkg = jn * 2 + kk;
      f32x4 d0 = *(const f32x4*)(DwH + kkg * 16);      // LDS broadcast reads
      f32x4 d1 = *(const f32x4*)(DwH + kkg * 16 + 8);
      unsigned bts[2] = {kk ? (dwm0 >> 16) : (dwm0 & 0xffffu),
                         kk ? (dwm1 >> 16) : (dwm1 & 0xffffu)};
#pragma unroll
      for (int f = 0; f < 2; ++f) {
        float Af = f ? Ac1 : Ac0, Bf_ = f ? Bc1 : Bc0;
        unsigned bt = bts[f];
        float pv[8];
#pragma unroll
        for (int s = 0; s < 8; ++s) {
          float dd = (s < 4) ? d0[s] : d1[s - 4];
          int kloc = 4 * g2 + (s & 3) + 8 * (s >> 2);
          float uu = fmaxf(Af + dd, fmaf(0.2f, dd, Bf_));
          float bfv = (float)((bt >> kloc) & 1u);
          pv[s] = __builtin_amdgcn_exp2f(fmaf(bfv, 1000.0f, uu));  // masked -> 0
        }
        union { h16x2 h2[4]; h16x8 h8; } uq;
        uq.h2[0] = __builtin_amdgcn_cvt_pkrtz(pv[0], pv[1]);
        uq.h2[1] = __builtin_amdgcn_cvt_pkrtz(pv[2], pv[3]);
        uq.h2[2] = __builtin_amdgcn_cvt_pkrtz(pv[4], pv[5]);
        uq.h2[3] = __builtin_amdgcn_cvt_pkrtz(pv[6], pv[7]);
        float ds = f ? dsum1 : dsum0;
#if __has_builtin(__builtin_amdgcn_fdot2)
        ds = __builtin_amdgcn_fdot2(uq.h2[0], ones, ds, false);
        ds = __builtin_amdgcn_fdot2(uq.h2[1], ones, ds, false);
        ds = __builtin_amdgcn_fdot2(uq.h2[2], ones, ds, false);
        ds = __builtin_amdgcn_fdot2(uq.h2[3], ones, ds, false);
#else
        ds += ((pv[0] + pv[1]) + (pv[2] + pv[3])) + ((pv[4] + pv[5]) + (pv[6] + pv[7]));
#endif
        if (f) dsum1 = ds; else dsum0 = ds;
        P[f][kk] = uq.h8;
      }
    }
  };

  auto MFMA_STEP = [&](const h16x8* Bc) {
#pragma unroll
    for (int kk = 0; kk < 2; ++kk)
#pragma unroll
      for (int nf = 0; nf < 4; ++nf) {
        acc[0][nf] = __builtin_amdgcn_mfma_f32_32x32x16_f16(P[0][kk], Bc[kk * 4 + nf], acc[0][nf], 0, 0, 0);
        acc[1][nf] = __builtin_amdgcn_mfma_f32_32x32x16_f16(P[1][kk], Bc[kk * 4 + nf], acc[1][nf], 0, 0, 0);
      }
  };

  LOADB(0, BA);
  __syncthreads();   // D window ready (compiler drains vmcnt before barrier)

  for (int j4 = 0; j4 < 8; ++j4) {
#pragma unroll
    for (int u = 0; u < 4; ++u) {
      const int jstep = j4 * 4 + u;
      h16x8* Bc = (u & 1) ? BB : BA;
      h16x8* Bn = (u & 1) ? BA : BB;
      if (jstep < 31) LOADB(jstep + 1, Bn);   // prefetch next B (L2-hit)
      SOFTMAX(jstep, (unsigned)mreg0[u], (unsigned)mreg1[u]);
      if (u == 3 && j4 < 7) {                 // shift AFTER last use of mreg
        mreg0 = mnext0; mreg1 = mnext1;
        if (j4 < 6) {
          mnext0 = *(const i32x4*)(mrow0 + (j4 + 2) * 8);
          mnext1 = *(const i32x4*)(mrow1 + (j4 + 2) * 8);
        }
      }
      MFMA_STEP(Bc);
    }
  }

  // denom: lanes l and l+32 share a row
  dsum0 += __shfl_xor(dsum0, 32);
  dsum1 += __shfl_xor(dsum1, 32);
  if (g2 == 0) {
    DEN[(size_t)(js * 2 + h) * NN + row0] = dsum0;
    DEN[(size_t)(js * 2 + h) * NN + row1] = dsum1;
  }
  // C layout (32x32): col = lr, crow = (r&3)+8*(r>>2)+4*g2
#pragma unroll
  for (int f = 0; f < 2; ++f) {
    __fp16* nb = NUM + ((size_t)(js * 2 + h) * NN + base + f * 32) * 128 + lr;
#pragma unroll
    for (int nf = 0; nf < 4; ++nf)
#pragma unroll
      for (int r = 0; r < 16; ++r) {
        int crow = (r & 3) + 8 * (r >> 2) + 4 * g2;
        nb[(size_t)crow * 128 + nf * 32] = (__fp16)acc[f][nf][r];
      }
  }
}

// ---------------- K3: merge js partials, combine heads, ELU
__global__ __launch_bounds__(256) void k3_out(const __fp16* __restrict__ NUM,
                                              const float* __restrict__ DEN,
                                              float* __restrict__ out) {
  int gid = blockIdx.x * 256 + threadIdx.x;  // 262144
  int i = gid >> 5;
  int c4 = (gid & 31) * 4;
  f32x4 n1 = {0.f, 0.f, 0.f, 0.f}, n2 = {0.f, 0.f, 0.f, 0.f};
  float d1 = 0.f, d2 = 0.f;
#pragma unroll
  for (int js = 0; js < 8; ++js) {
    h16x4 a1v = *(const h16x4*)(NUM + ((size_t)(js * 2 + 0) * NN + i) * 128 + c4);
    h16x4 a2v = *(const h16x4*)(NUM + ((size_t)(js * 2 + 1) * NN + i) * 128 + c4);
#pragma unroll
    for (int e = 0; e < 4; ++e) { n1[e] += (float)a1v[e]; n2[e] += (float)a2v[e]; }
    d1 += DEN[(size_t)(js * 2 + 0) * NN + i];
    d2 += DEN[(size_t)(js * 2 + 1) * NN + i];
  }
  float r1 = 1.0f / d1, r2 = 0.5f / d2;
  f32x4 o;
#pragma unroll
  for (int e = 0; e < 4; ++e) {
    float x = n1[e] * r1 + n2[e] * r2;
    o[e] = x > 0.f ? x : (exp2f(x * LOG2E) - 1.0f);
  }
  *(f32x4*)(out + (size_t)i * 128 + c4) = o;
}

extern "C" void kernel_launch(void* const* d_in, const int* in_sizes, int n_in,
                              void* d_out, int out_size, void* d_ws, size_t ws_size,
                              hipStream_t stream) {
  const float* inp = (const float*)d_in[0];
  const int* adj = (const int*)d_in[1];
  const float* W1 = (const float*)d_in[2];
  const float* a1 = (const float*)d_in[3];
  const float* W2 = (const float*)d_in[4];
  const float* a2 = (const float*)d_in[5];
  float* out = (float*)d_out;
  char* ws = (char*)d_ws;
  // ws layout (~46.9 MB):
  __fp16* WT = (__fp16*)(ws);                              // 128 KB
  __fp16* hT2 = (__fp16*)(ws + 131072);                    // 4 MB
  float* S = (float*)(ws + 4325376);                       // 64 KB
  float* D = (float*)(ws + 4390912);                       // 64 KB
  unsigned* GMu = (unsigned*)(ws + 4456448);               // 256 B
  unsigned short* adjb = (unsigned short*)(ws + 4456704);  // 8 MB row-major
  __fp16* NUM = (__fp16*)(ws + 12845312);                  // 32 MB
  float* DEN = (float*)(ws + 46399744);                    // 512 KB

  k0_wt<<<dim3(32), dim3(256), 0, stream>>>(W1, W2, WT, GMu);
  kf<<<dim3(2304), dim3(256), 0, stream>>>(adj, adjb, inp, WT, a1, a2, hT2, S, D, GMu);
  k2_attn<<<dim3(512), dim3(256), 0, stream>>>(adjb, hT2, S, D, GMu, NUM, DEN);
  k3_out<<<dim3(1024), dim3(256), 0, stream>>>(NUM, DEN, out);
}

// Round 13
// 157.719 us; speedup vs baseline: 1.1141x; 1.1141x over previous
//
#include <hip/hip_runtime.h>
#include <hip/hip_fp16.h>

#define NN 8192
#define INF 256
#define OUTF 128
#define LOG2E 1.44269504088896340736f

typedef float f32x4 __attribute__((ext_vector_type(4)));
typedef float f32x16 __attribute__((ext_vector_type(16)));
typedef __fp16 h16x8 __attribute__((ext_vector_type(8)));
typedef __fp16 h16x4 __attribute__((ext_vector_type(4)));
typedef __fp16 h16x2 __attribute__((ext_vector_type(2)));
typedef int i32x4 __attribute__((ext_vector_type(4)));

__device__ __forceinline__ void gload_lds16(const void* g, void* l) {
  __builtin_amdgcn_global_load_lds(
      (const __attribute__((address_space(1))) unsigned int*)g,
      (__attribute__((address_space(3))) unsigned int*)l, 16, 0, 0);
}

// order-preserving float->uint encoding (for atomicMax-based global max)
__device__ __forceinline__ unsigned encf(float f) {
  int b = __float_as_int(f);
  return b >= 0 ? ((unsigned)b | 0x80000000u) : ~(unsigned)b;
}
__device__ __forceinline__ float decf(unsigned u) {
  int b = (u & 0x80000000u) ? (int)(u & 0x7FFFFFFFu) : ~(int)u;
  return __int_as_float(b);
}

// ---------------- K0: W -> WT_perm f16; also zeroes GMu (runs before k1)
__global__ __launch_bounds__(256) void k0_wt(const float* __restrict__ W1,
                                             const float* __restrict__ W2,
                                             __fp16* __restrict__ WT,
                                             unsigned* __restrict__ GMu) {
  if (blockIdx.x == 0 && threadIdx.x < 2) GMu[threadIdx.x] = 0u;
  int m = blockIdx.x * 256 + threadIdx.x;  // 8192 chunks of 16B
  int h = m >> 12;
  int r = m & 4095;
  int c = r >> 5;
  int kb = (r >> 1) & 15;
  int hh = r & 1;
  const float* W = h ? W2 : W1;
  float v[8];
#pragma unroll
  for (int s = 0; s < 8; ++s) {
    int koff = 4 * hh + (s & 3) + 8 * (s >> 2);
    v[s] = W[(kb * 16 + koff) * OUTF + c];
  }
  union { h16x2 h2[4]; i32x4 q; } u;
  u.h2[0] = __builtin_amdgcn_cvt_pkrtz(v[0], v[1]);
  u.h2[1] = __builtin_amdgcn_cvt_pkrtz(v[2], v[3]);
  u.h2[2] = __builtin_amdgcn_cvt_pkrtz(v[4], v[5]);
  u.h2[3] = __builtin_amdgcn_cvt_pkrtz(v[6], v[7]);
  *(i32x4*)(WT + (size_t)h * 32768 + c * 256 + kb * 16 + hh * 8) = u.q;
}

// ---------------- K1: h = inp@W via MFMA; emits hT2 (32x32x16 B-frag layout),
// src'/dst' scaled by log2e; atomicMax global dst'-max.
__global__ __launch_bounds__(128) void k1_h(
    const float* __restrict__ inp, const __fp16* __restrict__ WT,
    const float* __restrict__ a1, const float* __restrict__ a2,
    __fp16* __restrict__ hT2, float* __restrict__ S, float* __restrict__ D,
    unsigned* __restrict__ GMu) {
  __shared__ __align__(16) float hl[2][32][136];
  int tid = threadIdx.x;
  int w = tid >> 6;           // wave = head
  int l = tid & 63;
  int lr = l & 31, g = l >> 5;
  int i0 = blockIdx.x * 32;
  const __fp16* WTh = WT + (size_t)w * 32768;
  f32x16 acc[4];
#pragma unroll
  for (int nf = 0; nf < 4; ++nf)
#pragma unroll
    for (int e = 0; e < 16; ++e) acc[nf][e] = 0.0f;
  const float* ip = inp + (size_t)(i0 + lr) * INF;
#pragma unroll
  for (int kb = 0; kb < 16; ++kb) {
    f32x4 q0 = *(const f32x4*)(ip + kb * 16 + 4 * g);
    f32x4 q1 = *(const f32x4*)(ip + kb * 16 + 8 + 4 * g);
    union { h16x2 h2[4]; h16x8 h8; } ua;
    ua.h2[0] = __builtin_amdgcn_cvt_pkrtz(q0[0], q0[1]);
    ua.h2[1] = __builtin_amdgcn_cvt_pkrtz(q0[2], q0[3]);
    ua.h2[2] = __builtin_amdgcn_cvt_pkrtz(q1[0], q1[1]);
    ua.h2[3] = __builtin_amdgcn_cvt_pkrtz(q1[2], q1[3]);
#pragma unroll
    for (int nf = 0; nf < 4; ++nf) {
      h16x8 b = *(const h16x8*)(WTh + (nf * 32 + lr) * 256 + kb * 16 + g * 8);
      acc[nf] = __builtin_amdgcn_mfma_f32_32x32x16_f16(ua.h8, b, acc[nf], 0, 0, 0);
    }
  }
#pragma unroll
  for (int nf = 0; nf < 4; ++nf)
#pragma unroll
    for (int r = 0; r < 16; ++r) {
      int row = (r & 3) + 8 * (r >> 2) + 4 * g;
      hl[w][row][nf * 32 + lr] = acc[nf][r];
    }
  __syncthreads();
  const float* av = w ? a2 : a1;
  float s = 0.f, d = 0.f;
#pragma unroll
  for (int cc = 0; cc < 64; cc += 4) {
    int c = g * 64 + cc;
    f32x4 hv = *(const f32x4*)&hl[w][lr][c];
    f32x4 as = *(const f32x4*)(av + c);
    f32x4 ad = *(const f32x4*)(av + 128 + c);
    s += hv[0] * as[0] + hv[1] * as[1] + hv[2] * as[2] + hv[3] * as[3];
    d += hv[0] * ad[0] + hv[1] * ad[1] + hv[2] * ad[2] + hv[3] * ad[3];
  }
  s += __shfl_xor(s, 32);
  d += __shfl_xor(d, 32);
  float dl = d * LOG2E;
  if (g == 0) {
    S[(size_t)w * NN + i0 + lr] = s * LOG2E;
    D[(size_t)w * NN + i0 + lr] = dl;
  }
  float dmax = dl;
#pragma unroll
  for (int off = 1; off < 32; off <<= 1) dmax = fmaxf(dmax, __shfl_xor(dmax, off));
  if (l == 0) atomicMax(GMu + w, encf(dmax));
  // hT2 emission
  __fp16* hTh = hT2 + (size_t)w * (NN * OUTF);
#pragma unroll
  for (int it = 0; it < 8; ++it) {
    int id = it * 64 + l;           // [0,512)
    int jb = id >> 8;
    int sub = id & 255;
    int nf = sub >> 6, lq = sub & 63;
    int lqr = lq & 31, lqg = lq >> 5;
    float v[8];
#pragma unroll
    for (int s2 = 0; s2 < 8; ++s2) {
      int kloc = 4 * lqg + (s2 & 3) + 8 * (s2 >> 2);   // MFMA k-map (A/B identical)
      v[s2] = hl[w][jb * 16 + kloc][nf * 32 + lqr];
    }
    union { h16x2 h2[4]; i32x4 q; } u2;
    u2.h2[0] = __builtin_amdgcn_cvt_pkrtz(v[0], v[1]);
    u2.h2[1] = __builtin_amdgcn_cvt_pkrtz(v[2], v[3]);
    u2.h2[2] = __builtin_amdgcn_cvt_pkrtz(v[4], v[5]);
    u2.h2[3] = __builtin_amdgcn_cvt_pkrtz(v[6], v[7]);
    *(i32x4*)(hTh + (size_t)((i0 >> 4) + jb) * 2048 + sub * 8) = u2.q;
  }
}

// ---------------- K2: ADJ-STREAMING bitmask softmax + PV, 32x32x16 MFMA.
// The 256MB adj stream is read INSIDE this kernel (coalesced: one wave per
// row, 1KB/instr), ballot-packed into a 10KB LDS mask ring (2 groups x 128
// rows x 40B; 8 jsteps/group). The whole K-loop is HBM-paced (~1.3us/jstep)
// and compute hides under the stream. Structure otherwise = r10 (best).
__global__ __launch_bounds__(256, 2) void k2_attn(
    const int* __restrict__ adj, const __fp16* __restrict__ hT2,
    const float* __restrict__ S, const float* __restrict__ D,
    const unsigned* __restrict__ GMu, __fp16* __restrict__ NUM,
    float* __restrict__ DEN) {
  __shared__ __align__(16) char smem[32768];     // hT dbuf: 2 x (2kk x 2heads x 4KB)
  __shared__ __align__(16) char maskL[10240];    // 2 slots x 128 rows x 40B (4 u64 + pad)
  int tid = threadIdx.x;
  int w = tid >> 6;
  int l = tid & 63;
  int lr = l & 31, g2 = l >> 5;
  int h = w >> 1, rq = w & 1;
  int rb = blockIdx.x >> 3, js = blockIdx.x & 7;
  int i0 = rb * 128;
  int jwin = js * 1024;
  int base = i0 + rq * 64;
  int row0 = base + lr, row1 = base + 32 + lr;
  float gm = decf(GMu[h]);
  float sf0 = S[(size_t)h * NN + row0];
  float sf1 = S[(size_t)h * NN + row1];
  float t0 = sf0 + gm, t1 = sf1 + gm;
  float cn0 = -fmaxf(t0, 0.2f * t0) - 1000.0f;
  float cn1 = -fmaxf(t1, 0.2f * t1) - 1000.0f;
  float Ac0 = sf0 + cn0, Bc0 = 0.2f * sf0 + cn0;
  float Ac1 = sf1 + cn1, Bc1 = 0.2f * sf1 + cn1;
  const float* Dh = D + (size_t)h * NN + jwin + 4 * g2;

  f32x16 acc[2][4];
#pragma unroll
  for (int f = 0; f < 2; ++f)
#pragma unroll
    for (int nf = 0; nf < 4; ++nf)
#pragma unroll
      for (int e = 0; e < 16; ++e) acc[f][nf][e] = 0.0f;
  float dsum0 = 0.f, dsum1 = 0.f;

  auto STAGE = [&](int jstep, int b) {
#pragma unroll
    for (int q = 0; q < 4; ++q) {          // q = kk_l*2 + hh
      int kk_l = q >> 1, hh = q & 1;
      const __fp16* gs = hT2 + (size_t)hh * (NN * OUTF) +
                         (size_t)(js * 64 + jstep * 2 + kk_l) * 2048 + tid * 8;
      gload_lds16(gs, smem + b * 16384 + q * 4096 + tid * 16);
    }
  };

  // PRODUCE: pack masks for group gg (j = jwin + gg*256 .. +255), 4 rows
  // starting at block-row r4 (this wave). Whole wave reads one row per instr
  // (lane l -> ints j=4l..4l+3): coalesced 1KB. ballot e bit l <-> j=4l+e.
  auto PRODUCE = [&](int gg, int r4) {
    const int* ab = adj + (size_t)(i0 + r4) * NN + jwin + gg * 256 + l * 4;
    i32x4 vv0 = *(const i32x4*)(ab);
    i32x4 vv1 = *(const i32x4*)(ab + NN);
    i32x4 vv2 = *(const i32x4*)(ab + 2 * NN);
    i32x4 vv3 = *(const i32x4*)(ab + 3 * NN);
    char* mrow = maskL + (gg & 1) * 5120 + r4 * 40 + l * 8;
#pragma unroll
    for (int rr = 0; rr < 4; ++rr) {
      i32x4 vv = rr == 0 ? vv0 : rr == 1 ? vv1 : rr == 2 ? vv2 : vv3;
      unsigned long long b0 = __ballot(vv[0] != 0);
      unsigned long long b1 = __ballot(vv[1] != 0);
      unsigned long long b2 = __ballot(vv[2] != 0);
      unsigned long long b3 = __ballot(vv[3] != 0);
      unsigned long long bsel = b0;
      bsel = (l == 1) ? b1 : bsel;
      bsel = (l == 2) ? b2 : bsel;
      bsel = (l == 3) ? b3 : bsel;
      if (l < 4) *(unsigned long long*)(mrow + rr * 40) = bsel;
    }
  };

  // consumer: u32 for (slot, block-row r, jstep-in-group u); bit n=e*8+i <-> jj=4i+e
  auto MASK32 = [&](int slot, int r, int u) -> unsigned {
    const unsigned char* mb = (const unsigned char*)(maskL + slot * 5120 + r * 40 + u);
    unsigned m0 = mb[0], m1 = mb[8], m2 = mb[16], m3 = mb[24];
    return m0 | (m1 << 8) | (m2 << 16) | (m3 << 24);
  };

  const h16x2 ones = {(__fp16)1.0f, (__fp16)1.0f};
  h16x8 P[2][2];

  // softmax for jstep (slot, u): masks from LDS ring; slot bit is compile-time
  // after pre-shifting by g2: bit' = 8*(s&3) + 4*kk + 2*(s>>2).
  auto SOFTMAX = [&](int jstep, int slot, int u) {
    unsigned bts0 = MASK32(slot, rq * 64 + lr, u) >> g2;
    unsigned bts1 = MASK32(slot, rq * 64 + 32 + lr, u) >> g2;
#pragma unroll
    for (int kk = 0; kk < 2; ++kk) {
      int kkg = jstep * 2 + kk;
      f32x4 d0 = *(const f32x4*)(Dh + kkg * 16);
      f32x4 d1 = *(const f32x4*)(Dh + kkg * 16 + 8);
#pragma unroll
      for (int f = 0; f < 2; ++f) {
        float Af = f ? Ac1 : Ac0, Bf_ = f ? Bc1 : Bc0;
        unsigned bts = f ? bts1 : bts0;
        float pv[8];
#pragma unroll
        for (int s = 0; s < 8; ++s) {
          float dd = (s < 4) ? d0[s] : d1[s - 4];
          const int bitp = 8 * (s & 3) + 4 * kk + 2 * (s >> 2);  // compile-time
          float uu = fmaxf(Af + dd, fmaf(0.2f, dd, Bf_));
          float bfv = (float)((bts >> bitp) & 1u);
          pv[s] = __builtin_amdgcn_exp2f(fmaf(bfv, 1000.0f, uu));  // masked -> 0
        }
        union { h16x2 h2[4]; h16x8 h8; } uq;
        uq.h2[0] = __builtin_amdgcn_cvt_pkrtz(pv[0], pv[1]);
        uq.h2[1] = __builtin_amdgcn_cvt_pkrtz(pv[2], pv[3]);
        uq.h2[2] = __builtin_amdgcn_cvt_pkrtz(pv[4], pv[5]);
        uq.h2[3] = __builtin_amdgcn_cvt_pkrtz(pv[6], pv[7]);
        float ds = f ? dsum1 : dsum0;
#if __has_builtin(__builtin_amdgcn_fdot2)
        ds = __builtin_amdgcn_fdot2(uq.h2[0], ones, ds, false);
        ds = __builtin_amdgcn_fdot2(uq.h2[1], ones, ds, false);
        ds = __builtin_amdgcn_fdot2(uq.h2[2], ones, ds, false);
        ds = __builtin_amdgcn_fdot2(uq.h2[3], ones, ds, false);
#else
        ds += ((pv[0] + pv[1]) + (pv[2] + pv[3])) + ((pv[4] + pv[5]) + (pv[6] + pv[7]));
#endif
        if (f) dsum1 = ds; else dsum0 = ds;
        P[f][kk] = uq.h8;
      }
    }
  };

  auto MFMA_STEP = [&](int b) {
#pragma unroll
    for (int kk = 0; kk < 2; ++kk) {
      const char* lb = smem + b * 16384 + (kk * 2 + h) * 4096 + l * 16;
#pragma unroll
      for (int nf = 0; nf < 4; ++nf) {
        h16x8 Bf = *(const h16x8*)(lb + nf * 1024);
        acc[0][nf] = __builtin_amdgcn_mfma_f32_32x32x16_f16(P[0][kk], Bf, acc[0][nf], 0, 0, 0);
        acc[1][nf] = __builtin_amdgcn_mfma_f32_32x32x16_f16(P[1][kk], Bf, acc[1][nf], 0, 0, 0);
      }
    }
  };

  // prologue: produce mask group 0 (8 chunks x 4 rows per wave), stage jstep 0
  STAGE(0, 0);
#pragma unroll
  for (int c = 0; c < 8; ++c) PRODUCE(0, w * 32 + c * 4);
  __syncthreads();

  for (int g = 0; g < 4; ++g) {
#pragma unroll
    for (int u = 0; u < 8; ++u) {
      const int jstep = g * 8 + u;
      const int b = jstep & 1;
      if (jstep < 31) STAGE(jstep + 1, b ^ 1);
      if (g < 3) PRODUCE(g + 1, w * 32 + u * 4);   // stream next group's adj
      SOFTMAX(jstep, g & 1, u);
      MFMA_STEP(b);
      __syncthreads();
    }
  }

  // denom: lanes l and l+32 share a row
  dsum0 += __shfl_xor(dsum0, 32);
  dsum1 += __shfl_xor(dsum1, 32);
  if (g2 == 0) {
    DEN[(size_t)(js * 2 + h) * NN + row0] = dsum0;
    DEN[(size_t)(js * 2 + h) * NN + row1] = dsum1;
  }
  // C layout (32x32): col = lr, crow = (r&3)+8*(r>>2)+4*g2
#pragma unroll
  for (int f = 0; f < 2; ++f) {
    __fp16* nb = NUM + ((size_t)(js * 2 + h) * NN + base + f * 32) * 128 + lr;
#pragma unroll
    for (int nf = 0; nf < 4; ++nf)
#pragma unroll
      for (int r = 0; r < 16; ++r) {
        int crow = (r & 3) + 8 * (r >> 2) + 4 * g2;
        nb[(size_t)crow * 128 + nf * 32] = (__fp16)acc[f][nf][r];
      }
  }
}

// ---------------- K3: merge js partials, combine heads, ELU
__global__ __launch_bounds__(256) void k3_out(const __fp16* __restrict__ NUM,
                                              const float* __restrict__ DEN,
                                              float* __restrict__ out) {
  int gid = blockIdx.x * 256 + threadIdx.x;  // 262144
  int i = gid >> 5;
  int c4 = (gid & 31) * 4;
  f32x4 n1 = {0.f, 0.f, 0.f, 0.f}, n2 = {0.f, 0.f, 0.f, 0.f};
  float d1 = 0.f, d2 = 0.f;
#pragma unroll
  for (int js = 0; js < 8; ++js) {
    h16x4 a1v = *(const h16x4*)(NUM + ((size_t)(js * 2 + 0) * NN + i) * 128 + c4);
    h16x4 a2v = *(const h16x4*)(NUM + ((size_t)(js * 2 + 1) * NN + i) * 128 + c4);
#pragma unroll
    for (int e = 0; e < 4; ++e) { n1[e] += (float)a1v[e]; n2[e] += (float)a2v[e]; }
    d1 += DEN[(size_t)(js * 2 + 0) * NN + i];
    d2 += DEN[(size_t)(js * 2 + 1) * NN + i];
  }
  float r1 = 1.0f / d1, r2 = 0.5f / d2;
  f32x4 o;
#pragma unroll
  for (int e = 0; e < 4; ++e) {
    float x = n1[e] * r1 + n2[e] * r2;
    o[e] = x > 0.f ? x : (exp2f(x * LOG2E) - 1.0f);
  }
  *(f32x4*)(out + (size_t)i * 128 + c4) = o;
}

extern "C" void kernel_launch(void* const* d_in, const int* in_sizes, int n_in,
                              void* d_out, int out_size, void* d_ws, size_t ws_size,
                              hipStream_t stream) {
  const float* inp = (const float*)d_in[0];
  const int* adj = (const int*)d_in[1];
  const float* W1 = (const float*)d_in[2];
  const float* a1 = (const float*)d_in[3];
  const float* W2 = (const float*)d_in[4];
  const float* a2 = (const float*)d_in[5];
  float* out = (float*)d_out;
  char* ws = (char*)d_ws;
  // ws layout (~46.9 MB):
  __fp16* WT = (__fp16*)(ws);                              // 128 KB
  __fp16* hT2 = (__fp16*)(ws + 131072);                    // 4 MB
  float* S = (float*)(ws + 4325376);                       // 64 KB
  float* D = (float*)(ws + 4390912);                       // 64 KB
  unsigned* GMu = (unsigned*)(ws + 4456448);               // 256 B
  __fp16* NUM = (__fp16*)(ws + 12845312);                  // 32 MB
  float* DEN = (float*)(ws + 46399744);                    // 512 KB

  k0_wt<<<dim3(32), dim3(256), 0, stream>>>(W1, W2, WT, GMu);
  k1_h<<<dim3(256), dim3(128), 0, stream>>>(inp, WT, a1, a2, hT2, S, D, GMu);
  k2_attn<<<dim3(512), dim3(256), 0, stream>>>(adj, hT2, S, D, GMu, NUM, DEN);
  k3_out<<<dim3(1024), dim3(256), 0, stream>>>(NUM, DEN, out);
}

// Round 14
// 117.219 us; speedup vs baseline: 1.4990x; 1.3455x over previous
//
#include <hip/hip_runtime.h>
#include <hip/hip_fp16.h>

#define NN 8192
#define INF 256
#define OUTF 128
#define LOG2E 1.44269504088896340736f

typedef float f32x4 __attribute__((ext_vector_type(4)));
typedef float f32x16 __attribute__((ext_vector_type(16)));
typedef __fp16 h16x8 __attribute__((ext_vector_type(8)));
typedef __fp16 h16x4 __attribute__((ext_vector_type(4)));
typedef __fp16 h16x2 __attribute__((ext_vector_type(2)));
typedef int i32x4 __attribute__((ext_vector_type(4)));

__device__ __forceinline__ void gload_lds16(const void* g, void* l) {
  __builtin_amdgcn_global_load_lds(
      (const __attribute__((address_space(1))) unsigned int*)g,
      (__attribute__((address_space(3))) unsigned int*)l, 16, 0, 0);
}

// order-preserving float->uint encoding (for atomicMax-based global max)
__device__ __forceinline__ unsigned encf(float f) {
  int b = __float_as_int(f);
  return b >= 0 ? ((unsigned)b | 0x80000000u) : ~(unsigned)b;
}
__device__ __forceinline__ float decf(unsigned u) {
  int b = (u & 0x80000000u) ? (int)(u & 0x7FFFFFFFu) : ~(int)u;
  return __int_as_float(b);
}

// ---------------- K0: W -> WT_perm f16; also zeroes GMu (runs before k1)
__global__ __launch_bounds__(256) void k0_wt(const float* __restrict__ W1,
                                             const float* __restrict__ W2,
                                             __fp16* __restrict__ WT,
                                             unsigned* __restrict__ GMu) {
  if (blockIdx.x == 0 && threadIdx.x < 2) GMu[threadIdx.x] = 0u;
  int m = blockIdx.x * 256 + threadIdx.x;  // 8192 chunks of 16B
  int h = m >> 12;
  int r = m & 4095;
  int c = r >> 5;
  int kb = (r >> 1) & 15;
  int hh = r & 1;
  const float* W = h ? W2 : W1;
  float v[8];
#pragma unroll
  for (int s = 0; s < 8; ++s) {
    int koff = 4 * hh + (s & 3) + 8 * (s >> 2);
    v[s] = W[(kb * 16 + koff) * OUTF + c];
  }
  union { h16x2 h2[4]; i32x4 q; } u;
  u.h2[0] = __builtin_amdgcn_cvt_pkrtz(v[0], v[1]);
  u.h2[1] = __builtin_amdgcn_cvt_pkrtz(v[2], v[3]);
  u.h2[2] = __builtin_amdgcn_cvt_pkrtz(v[4], v[5]);
  u.h2[3] = __builtin_amdgcn_cvt_pkrtz(v[6], v[7]);
  *(i32x4*)(WT + (size_t)h * 32768 + c * 256 + kb * 16 + hh * 8) = u.q;
}

// ---------------- K1: h = inp@W via MFMA; emits hT2 (32x32x16 B-frag layout),
// src'/dst' scaled by log2e; atomicMax global dst'-max.
__global__ __launch_bounds__(128) void k1_h(
    const float* __restrict__ inp, const __fp16* __restrict__ WT,
    const float* __restrict__ a1, const float* __restrict__ a2,
    __fp16* __restrict__ hT2, float* __restrict__ S, float* __restrict__ D,
    unsigned* __restrict__ GMu) {
  __shared__ __align__(16) float hl[2][32][136];
  int tid = threadIdx.x;
  int w = tid >> 6;           // wave = head
  int l = tid & 63;
  int lr = l & 31, g = l >> 5;
  int i0 = blockIdx.x * 32;
  const __fp16* WTh = WT + (size_t)w * 32768;
  f32x16 acc[4];
#pragma unroll
  for (int nf = 0; nf < 4; ++nf)
#pragma unroll
    for (int e = 0; e < 16; ++e) acc[nf][e] = 0.0f;
  const float* ip = inp + (size_t)(i0 + lr) * INF;
#pragma unroll
  for (int kb = 0; kb < 16; ++kb) {
    f32x4 q0 = *(const f32x4*)(ip + kb * 16 + 4 * g);
    f32x4 q1 = *(const f32x4*)(ip + kb * 16 + 8 + 4 * g);
    union { h16x2 h2[4]; h16x8 h8; } ua;
    ua.h2[0] = __builtin_amdgcn_cvt_pkrtz(q0[0], q0[1]);
    ua.h2[1] = __builtin_amdgcn_cvt_pkrtz(q0[2], q0[3]);
    ua.h2[2] = __builtin_amdgcn_cvt_pkrtz(q1[0], q1[1]);
    ua.h2[3] = __builtin_amdgcn_cvt_pkrtz(q1[2], q1[3]);
#pragma unroll
    for (int nf = 0; nf < 4; ++nf) {
      h16x8 b = *(const h16x8*)(WTh + (nf * 32 + lr) * 256 + kb * 16 + g * 8);
      acc[nf] = __builtin_amdgcn_mfma_f32_32x32x16_f16(ua.h8, b, acc[nf], 0, 0, 0);
    }
  }
#pragma unroll
  for (int nf = 0; nf < 4; ++nf)
#pragma unroll
    for (int r = 0; r < 16; ++r) {
      int row = (r & 3) + 8 * (r >> 2) + 4 * g;
      hl[w][row][nf * 32 + lr] = acc[nf][r];
    }
  __syncthreads();
  const float* av = w ? a2 : a1;
  float s = 0.f, d = 0.f;
#pragma unroll
  for (int cc = 0; cc < 64; cc += 4) {
    int c = g * 64 + cc;
    f32x4 hv = *(const f32x4*)&hl[w][lr][c];
    f32x4 as = *(const f32x4*)(av + c);
    f32x4 ad = *(const f32x4*)(av + 128 + c);
    s += hv[0] * as[0] + hv[1] * as[1] + hv[2] * as[2] + hv[3] * as[3];
    d += hv[0] * ad[0] + hv[1] * ad[1] + hv[2] * ad[2] + hv[3] * ad[3];
  }
  s += __shfl_xor(s, 32);
  d += __shfl_xor(d, 32);
  float dl = d * LOG2E;
  if (g == 0) {
    S[(size_t)w * NN + i0 + lr] = s * LOG2E;
    D[(size_t)w * NN + i0 + lr] = dl;
  }
  float dmax = dl;
#pragma unroll
  for (int off = 1; off < 32; off <<= 1) dmax = fmaxf(dmax, __shfl_xor(dmax, off));
  if (l == 0) atomicMax(GMu + w, encf(dmax));
  // hT2 emission
  __fp16* hTh = hT2 + (size_t)w * (NN * OUTF);
#pragma unroll
  for (int it = 0; it < 8; ++it) {
    int id = it * 64 + l;           // [0,512)
    int jb = id >> 8;
    int sub = id & 255;
    int nf = sub >> 6, lq = sub & 63;
    int lqr = lq & 31, lqg = lq >> 5;
    float v[8];
#pragma unroll
    for (int s2 = 0; s2 < 8; ++s2) {
      int kloc = 4 * lqg + (s2 & 3) + 8 * (s2 >> 2);   // MFMA k-map (A/B identical)
      v[s2] = hl[w][jb * 16 + kloc][nf * 32 + lqr];
    }
    union { h16x2 h2[4]; i32x4 q; } u2;
    u2.h2[0] = __builtin_amdgcn_cvt_pkrtz(v[0], v[1]);
    u2.h2[1] = __builtin_amdgcn_cvt_pkrtz(v[2], v[3]);
    u2.h2[2] = __builtin_amdgcn_cvt_pkrtz(v[4], v[5]);
    u2.h2[3] = __builtin_amdgcn_cvt_pkrtz(v[6], v[7]);
    *(i32x4*)(hTh + (size_t)((i0 >> 4) + jb) * 2048 + sub * 8) = u2.q;
  }
}

// ---------------- K2: ADJ-STREAMING bitmask softmax + PV, PIPELINED (T14).
// Loads for mask-chunk c are issued 2 jsteps before its ballot (named regs
// RA/RB selected by compile-time u&1). Ballot for group g+1 runs spread over
// group g's 8 jsteps into the 2-slot LDS ring. The per-jstep __syncthreads
// drains vmcnt, giving each load one full jstep (~1us) of slack >> 900cyc HBM.
__global__ __launch_bounds__(256, 2) void k2_attn(
    const int* __restrict__ adj, const __fp16* __restrict__ hT2,
    const float* __restrict__ S, const float* __restrict__ D,
    const unsigned* __restrict__ GMu, __fp16* __restrict__ NUM,
    float* __restrict__ DEN) {
  __shared__ __align__(16) char smem[32768];     // hT dbuf: 2 x (2kk x 2heads x 4KB)
  __shared__ __align__(16) char maskL[10240];    // 2 slots x 128 rows x 40B
  int tid = threadIdx.x;
  int w = tid >> 6;
  int l = tid & 63;
  int lr = l & 31, g2 = l >> 5;
  int h = w >> 1, rq = w & 1;
  int rb = blockIdx.x >> 3, js = blockIdx.x & 7;
  int i0 = rb * 128;
  int jwin = js * 1024;
  int base = i0 + rq * 64;
  int row0 = base + lr, row1 = base + 32 + lr;
  float gm = decf(GMu[h]);
  float sf0 = S[(size_t)h * NN + row0];
  float sf1 = S[(size_t)h * NN + row1];
  float t0 = sf0 + gm, t1 = sf1 + gm;
  float cn0 = -fmaxf(t0, 0.2f * t0) - 1000.0f;
  float cn1 = -fmaxf(t1, 0.2f * t1) - 1000.0f;
  float Ac0 = sf0 + cn0, Bc0 = 0.2f * sf0 + cn0;
  float Ac1 = sf1 + cn1, Bc1 = 0.2f * sf1 + cn1;
  const float* Dh = D + (size_t)h * NN + jwin + 4 * g2;

  f32x16 acc[2][4];
#pragma unroll
  for (int f = 0; f < 2; ++f)
#pragma unroll
    for (int nf = 0; nf < 4; ++nf)
#pragma unroll
      for (int e = 0; e < 16; ++e) acc[f][nf][e] = 0.0f;
  float dsum0 = 0.f, dsum1 = 0.f;

  auto STAGE = [&](int jstep, int b) {
#pragma unroll
    for (int q = 0; q < 4; ++q) {          // q = kk_l*2 + hh
      int kk_l = q >> 1, hh = q & 1;
      const __fp16* gs = hT2 + (size_t)hh * (NN * OUTF) +
                         (size_t)(js * 64 + jstep * 2 + kk_l) * 2048 + tid * 8;
      gload_lds16(gs, smem + b * 16384 + q * 4096 + tid * 16);
    }
  };

  struct Chunk { i32x4 v0, v1, v2, v3; };
  // chunk c (c=gg*8+u): rows i0+w*32+u*4 .. +3, cols jwin+gg*256+l*4 (coalesced 1KB/row)
  auto LOADC = [&](int c, Chunk& R) {
    int u = c & 7, gg = c >> 3;
    const int* ab = adj + (size_t)(i0 + w * 32 + u * 4) * NN + jwin + gg * 256 + l * 4;
    R.v0 = *(const i32x4*)(ab);
    R.v1 = *(const i32x4*)(ab + NN);
    R.v2 = *(const i32x4*)(ab + 2 * NN);
    R.v3 = *(const i32x4*)(ab + 3 * NN);
  };
  // ballot-pack chunk c into ring slot (gg&1). ballot e bit l <-> j=4l+e.
  auto BALLOT = [&](int c, const Chunk& R) {
    int u = c & 7, gg = c >> 3;
    char* mrow = maskL + (gg & 1) * 5120 + (w * 32 + u * 4) * 40 + l * 8;
#pragma unroll
    for (int rr = 0; rr < 4; ++rr) {
      i32x4 vv = rr == 0 ? R.v0 : rr == 1 ? R.v1 : rr == 2 ? R.v2 : R.v3;
      unsigned long long b0 = __ballot(vv[0] != 0);
      unsigned long long b1 = __ballot(vv[1] != 0);
      unsigned long long b2 = __ballot(vv[2] != 0);
      unsigned long long b3 = __ballot(vv[3] != 0);
      unsigned long long bsel = b0;
      bsel = (l == 1) ? b1 : bsel;
      bsel = (l == 2) ? b2 : bsel;
      bsel = (l == 3) ? b3 : bsel;
      if (l < 4) *(unsigned long long*)(mrow + rr * 40) = bsel;
    }
  };

  // consumer: u32 for (slot, block-row r, jstep-in-group u); bit n=e*8+i <-> jj=4i+e
  auto MASK32 = [&](int slot, int r, int u) -> unsigned {
    const unsigned char* mb = (const unsigned char*)(maskL + slot * 5120 + r * 40 + u);
    unsigned m0 = mb[0], m1 = mb[8], m2 = mb[16], m3 = mb[24];
    return m0 | (m1 << 8) | (m2 << 16) | (m3 << 24);
  };

  const h16x2 ones = {(__fp16)1.0f, (__fp16)1.0f};
  h16x8 P[2][2];

  auto SOFTMAX = [&](int jstep, int slot, int u) {
    unsigned bts0 = MASK32(slot, rq * 64 + lr, u) >> g2;
    unsigned bts1 = MASK32(slot, rq * 64 + 32 + lr, u) >> g2;
#pragma unroll
    for (int kk = 0; kk < 2; ++kk) {
      int kkg = jstep * 2 + kk;
      f32x4 d0 = *(const f32x4*)(Dh + kkg * 16);
      f32x4 d1 = *(const f32x4*)(Dh + kkg * 16 + 8);
#pragma unroll
      for (int f = 0; f < 2; ++f) {
        float Af = f ? Ac1 : Ac0, Bf_ = f ? Bc1 : Bc0;
        unsigned bts = f ? bts1 : bts0;
        float pv[8];
#pragma unroll
        for (int s = 0; s < 8; ++s) {
          float dd = (s < 4) ? d0[s] : d1[s - 4];
          const int bitp = 8 * (s & 3) + 4 * kk + 2 * (s >> 2);  // compile-time
          float uu = fmaxf(Af + dd, fmaf(0.2f, dd, Bf_));
          float bfv = (float)((bts >> bitp) & 1u);
          pv[s] = __builtin_amdgcn_exp2f(fmaf(bfv, 1000.0f, uu));  // masked -> 0
        }
        union { h16x2 h2[4]; h16x8 h8; } uq;
        uq.h2[0] = __builtin_amdgcn_cvt_pkrtz(pv[0], pv[1]);
        uq.h2[1] = __builtin_amdgcn_cvt_pkrtz(pv[2], pv[3]);
        uq.h2[2] = __builtin_amdgcn_cvt_pkrtz(pv[4], pv[5]);
        uq.h2[3] = __builtin_amdgcn_cvt_pkrtz(pv[6], pv[7]);
        float ds = f ? dsum1 : dsum0;
#if __has_builtin(__builtin_amdgcn_fdot2)
        ds = __builtin_amdgcn_fdot2(uq.h2[0], ones, ds, false);
        ds = __builtin_amdgcn_fdot2(uq.h2[1], ones, ds, false);
        ds = __builtin_amdgcn_fdot2(uq.h2[2], ones, ds, false);
        ds = __builtin_amdgcn_fdot2(uq.h2[3], ones, ds, false);
#else
        ds += ((pv[0] + pv[1]) + (pv[2] + pv[3])) + ((pv[4] + pv[5]) + (pv[6] + pv[7]));
#endif
        if (f) dsum1 = ds; else dsum0 = ds;
        P[f][kk] = uq.h8;
      }
    }
  };

  auto MFMA_STEP = [&](int b) {
#pragma unroll
    for (int kk = 0; kk < 2; ++kk) {
      const char* lb = smem + b * 16384 + (kk * 2 + h) * 4096 + l * 16;
#pragma unroll
      for (int nf = 0; nf < 4; ++nf) {
        h16x8 Bf = *(const h16x8*)(lb + nf * 1024);
        acc[0][nf] = __builtin_amdgcn_mfma_f32_32x32x16_f16(P[0][kk], Bf, acc[0][nf], 0, 0, 0);
        acc[1][nf] = __builtin_amdgcn_mfma_f32_32x32x16_f16(P[1][kk], Bf, acc[1][nf], 0, 0, 0);
      }
    }
  };

  // prologue: group 0 masks (serial), then prime the 2-deep chunk pipeline
  Chunk RA, RB;
#pragma unroll
  for (int c = 0; c < 8; ++c) { Chunk T; LOADC(c, T); BALLOT(c, T); }
  LOADC(8, RA);
  LOADC(9, RB);
  STAGE(0, 0);
  __syncthreads();

  for (int g = 0; g < 4; ++g) {
#pragma unroll
    for (int u = 0; u < 8; ++u) {
      const int jstep = g * 8 + u;
      const int b = u & 1;               // == jstep & 1
      if (jstep < 31) STAGE(jstep + 1, b ^ 1);
      if (g < 3) {                       // produce group g+1 = chunks jstep+8
        if (u & 1) { BALLOT(jstep + 8, RB); if (jstep + 10 < 32) LOADC(jstep + 10, RB); }
        else       { BALLOT(jstep + 8, RA); if (jstep + 10 < 32) LOADC(jstep + 10, RA); }
      }
      SOFTMAX(jstep, g & 1, u);
      MFMA_STEP(b);
      __syncthreads();
    }
  }

  // denom: lanes l and l+32 share a row
  dsum0 += __shfl_xor(dsum0, 32);
  dsum1 += __shfl_xor(dsum1, 32);
  if (g2 == 0) {
    DEN[(size_t)(js * 2 + h) * NN + row0] = dsum0;
    DEN[(size_t)(js * 2 + h) * NN + row1] = dsum1;
  }
  // C layout (32x32): col = lr, crow = (r&3)+8*(r>>2)+4*g2
#pragma unroll
  for (int f = 0; f < 2; ++f) {
    __fp16* nb = NUM + ((size_t)(js * 2 + h) * NN + base + f * 32) * 128 + lr;
#pragma unroll
    for (int nf = 0; nf < 4; ++nf)
#pragma unroll
      for (int r = 0; r < 16; ++r) {
        int crow = (r & 3) + 8 * (r >> 2) + 4 * g2;
        nb[(size_t)crow * 128 + nf * 32] = (__fp16)acc[f][nf][r];
      }
  }
}

// ---------------- K3: merge js partials, combine heads, ELU
__global__ __launch_bounds__(256) void k3_out(const __fp16* __restrict__ NUM,
                                              const float* __restrict__ DEN,
                                              float* __restrict__ out) {
  int gid = blockIdx.x * 256 + threadIdx.x;  // 262144
  int i = gid >> 5;
  int c4 = (gid & 31) * 4;
  f32x4 n1 = {0.f, 0.f, 0.f, 0.f}, n2 = {0.f, 0.f, 0.f, 0.f};
  float d1 = 0.f, d2 = 0.f;
#pragma unroll
  for (int js = 0; js < 8; ++js) {
    h16x4 a1v = *(const h16x4*)(NUM + ((size_t)(js * 2 + 0) * NN + i) * 128 + c4);
    h16x4 a2v = *(const h16x4*)(NUM + ((size_t)(js * 2 + 1) * NN + i) * 128 + c4);
#pragma unroll
    for (int e = 0; e < 4; ++e) { n1[e] += (float)a1v[e]; n2[e] += (float)a2v[e]; }
    d1 += DEN[(size_t)(js * 2 + 0) * NN + i];
    d2 += DEN[(size_t)(js * 2 + 1) * NN + i];
  }
  float r1 = 1.0f / d1, r2 = 0.5f / d2;
  f32x4 o;
#pragma unroll
  for (int e = 0; e < 4; ++e) {
    float x = n1[e] * r1 + n2[e] * r2;
    o[e] = x > 0.f ? x : (exp2f(x * LOG2E) - 1.0f);
  }
  *(f32x4*)(out + (size_t)i * 128 + c4) = o;
}

extern "C" void kernel_launch(void* const* d_in, const int* in_sizes, int n_in,
                              void* d_out, int out_size, void* d_ws, size_t ws_size,
                              hipStream_t stream) {
  const float* inp = (const float*)d_in[0];
  const int* adj = (const int*)d_in[1];
  const float* W1 = (const float*)d_in[2];
  const float* a1 = (const float*)d_in[3];
  const float* W2 = (const float*)d_in[4];
  const float* a2 = (const float*)d_in[5];
  float* out = (float*)d_out;
  char* ws = (char*)d_ws;
  // ws layout (~46.9 MB):
  __fp16* WT = (__fp16*)(ws);                              // 128 KB
  __fp16* hT2 = (__fp16*)(ws + 131072);                    // 4 MB
  float* S = (float*)(ws + 4325376);                       // 64 KB
  float* D = (float*)(ws + 4390912);                       // 64 KB
  unsigned* GMu = (unsigned*)(ws + 4456448);               // 256 B
  __fp16* NUM = (__fp16*)(ws + 12845312);                  // 32 MB
  float* DEN = (float*)(ws + 46399744);                    // 512 KB

  k0_wt<<<dim3(32), dim3(256), 0, stream>>>(W1, W2, WT, GMu);
  k1_h<<<dim3(256), dim3(128), 0, stream>>>(inp, WT, a1, a2, hT2, S, D, GMu);
  k2_attn<<<dim3(512), dim3(256), 0, stream>>>(adj, hT2, S, D, GMu, NUM, DEN);
  k3_out<<<dim3(1024), dim3(256), 0, stream>>>(NUM, DEN, out);
}